// Round 3
// baseline (483.874 us; speedup 1.0000x reference)
//
#include <hip/hip_runtime.h>
#include <cstddef>

// Dims fixed by the reference: input [T=128, B=256, D1=1024] fp32,
// weight [D2=512, D1=1024] fp32. Outputs spk/V/I each [T,B,D2] fp32 concat.
#define TT 128
#define BB 256
#define D1 1024
#define D2 512
#define SS (BB * D2)      // 131072 elems per timestep slice
#define MM (127 * BB)     // 32512 GEMM rows

#define ALPHA 0.8187307530779818f
#define BETA  0.9048374180359595f

typedef _Float16 half8 __attribute__((ext_vector_type(8)));
typedef _Float16 half4v __attribute__((ext_vector_type(4)));
typedef float floatx16 __attribute__((ext_vector_type(16)));

// ---------------------------------------------------------------------------
// W pre-convert: fp32 -> f16 hi + f16 lo*2048 planes (split-f16).
// Planes live in the spk region of d_out (slices 1..4), read by gemm from
// L2 (2 MB total, L2-resident), then overwritten by scan.
// ---------------------------------------------------------------------------
__global__ __launch_bounds__(256) void convert_w(const float* __restrict__ W,
                                                 _Float16* __restrict__ Whi,
                                                 _Float16* __restrict__ Wlo) {
    const int i = (blockIdx.x * 256 + threadIdx.x) * 4;
    float4 w = *(const float4*)(W + i);
    half4v hi, lo;
    hi.x = (_Float16)w.x; lo.x = (_Float16)((w.x - (float)hi.x) * 2048.0f);
    hi.y = (_Float16)w.y; lo.y = (_Float16)((w.y - (float)hi.y) * 2048.0f);
    hi.z = (_Float16)w.z; lo.z = (_Float16)((w.z - (float)hi.z) * 2048.0f);
    hi.w = (_Float16)w.w; lo.w = (_Float16)((w.w - (float)hi.w) * 2048.0f);
    *(half4v*)(Whi + i) = hi;
    *(half4v*)(Wlo + i) = lo;
}

// ---------------------------------------------------------------------------
// Split-f16 MFMA GEMM v3: C = hiA*hiB + 2^-11*(hiA*loB + loA*hiB).
// BM=64 x BN=256 x BK=32, 256 threads, wave-tile 64x64 (2x2 of 32x32x16).
// A: fp32 global -> hi/lo f16 -> LDS (stride LDH=40 f16 = 80 B: lane m start
//    bank = 20m mod 32 -> conflict-free for both b128 writes and frag reads).
// W: NO LDS. B-frag = 16 contiguous bytes at row n=lane&31 -> direct
//    global_load_dwordx4 from the L2-resident f16 planes, prefetched one
//    k-step ahead (kk=0 frags a full iteration ahead, behind the barrier).
// ---------------------------------------------------------------------------
#define BM 64
#define BN 256
#define BK 32
#define LDH 40

__global__ __launch_bounds__(256, 2) void gemm_mfma(const float* __restrict__ A,
                                                    const _Float16* __restrict__ Whi,
                                                    const _Float16* __restrict__ Wlo,
                                                    float* __restrict__ C) {
    __shared__ _Float16 Ah[BM * LDH];
    __shared__ _Float16 Al[BM * LDH];

    const int tid = threadIdx.x;
    const int lane = tid & 63;
    const int wv = tid >> 6;          // wave 0..3 -> n-offset wv*64
    const int bm = blockIdx.x * BM;
    const int bn = blockIdx.y * BN;

    // A staging: 4 threads per row, 8 consecutive fp32 each
    const int arow = tid >> 2;        // 0..63
    const int kch = (tid & 3) * 8;    // 0,8,16,24

    const int m_ = lane & 31;         // MFMA m/n index
    const int q = lane >> 5;          // k-quad

    // per-lane W fragment base pointers (element offsets)
    const _Float16* WhiB[2];
    const _Float16* WloB[2];
#pragma unroll
    for (int nb = 0; nb < 2; ++nb) {
        const size_t off = (size_t)(bn + wv * 64 + nb * 32 + m_) * D1 + q * 8;
        WhiB[nb] = Whi + off;
        WloB[nb] = Wlo + off;
    }

    floatx16 accm[2][2], accl[2][2];
#pragma unroll
    for (int i = 0; i < 2; ++i)
#pragma unroll
        for (int j = 0; j < 2; ++j) {
            accm[i][j] = (floatx16)0.0f;
            accl[i][j] = (floatx16)0.0f;
        }

    const float* Abase = A + (size_t)(bm + arow) * D1 + kch;

    // prefetch kk=0 B-frags for k0=0
    half8 bh0[2], bl0[2];
#pragma unroll
    for (int nb = 0; nb < 2; ++nb) {
        bh0[nb] = *(const half8*)(WhiB[nb]);
        bl0[nb] = *(const half8*)(WloB[nb]);
    }

    for (int k0 = 0; k0 < D1; k0 += BK) {
        // ---- A global loads ----
        float4 a0 = *(const float4*)(Abase + k0);
        float4 a1 = *(const float4*)(Abase + k0 + 4);

        // ---- kk=16 B-frags (used after kk=0's 12 MFMAs) ----
        half8 bh1[2], bl1[2];
#pragma unroll
        for (int nb = 0; nb < 2; ++nb) {
            bh1[nb] = *(const half8*)(WhiB[nb] + k0 + 16);
            bl1[nb] = *(const half8*)(WloB[nb] + k0 + 16);
        }

        __syncthreads();  // previous tile's LDS reads done

        // ---- convert A to hi/lo f16 and stage ----
        float av[8] = {a0.x, a0.y, a0.z, a0.w, a1.x, a1.y, a1.z, a1.w};
        half8 ah, al;
#pragma unroll
        for (int j = 0; j < 8; ++j) {
            _Float16 h = (_Float16)av[j];
            ah[j] = h;
            al[j] = (_Float16)((av[j] - (float)h) * 2048.0f);
        }
        *(half8*)&Ah[arow * LDH + kch] = ah;
        *(half8*)&Al[arow * LDH + kch] = al;
        __syncthreads();

        // ---- kk = 0 ----
        {
            const int ko = q * 8;
            half8 a_hi[2], a_lo[2];
#pragma unroll
            for (int mb = 0; mb < 2; ++mb) {
                a_hi[mb] = *(const half8*)&Ah[(mb * 32 + m_) * LDH + ko];
                a_lo[mb] = *(const half8*)&Al[(mb * 32 + m_) * LDH + ko];
            }
#pragma unroll
            for (int mb = 0; mb < 2; ++mb)
#pragma unroll
                for (int nb = 0; nb < 2; ++nb) {
                    accm[mb][nb] = __builtin_amdgcn_mfma_f32_32x32x16_f16(
                        a_hi[mb], bh0[nb], accm[mb][nb], 0, 0, 0);
                    accl[mb][nb] = __builtin_amdgcn_mfma_f32_32x32x16_f16(
                        a_hi[mb], bl0[nb], accl[mb][nb], 0, 0, 0);
                    accl[mb][nb] = __builtin_amdgcn_mfma_f32_32x32x16_f16(
                        a_lo[mb], bh0[nb], accl[mb][nb], 0, 0, 0);
                }
        }

        // ---- prefetch next iteration's kk=0 B-frags (hidden behind kk=16
        //      MFMAs + next iter's barrier/staging) ----
        const int kn = (k0 + BK < D1) ? (k0 + BK) : 0;
#pragma unroll
        for (int nb = 0; nb < 2; ++nb) {
            bh0[nb] = *(const half8*)(WhiB[nb] + kn);
            bl0[nb] = *(const half8*)(WloB[nb] + kn);
        }

        // ---- kk = 16 ----
        {
            const int ko = 16 + q * 8;
            half8 a_hi[2], a_lo[2];
#pragma unroll
            for (int mb = 0; mb < 2; ++mb) {
                a_hi[mb] = *(const half8*)&Ah[(mb * 32 + m_) * LDH + ko];
                a_lo[mb] = *(const half8*)&Al[(mb * 32 + m_) * LDH + ko];
            }
#pragma unroll
            for (int mb = 0; mb < 2; ++mb)
#pragma unroll
                for (int nb = 0; nb < 2; ++nb) {
                    accm[mb][nb] = __builtin_amdgcn_mfma_f32_32x32x16_f16(
                        a_hi[mb], bh1[nb], accm[mb][nb], 0, 0, 0);
                    accl[mb][nb] = __builtin_amdgcn_mfma_f32_32x32x16_f16(
                        a_hi[mb], bl1[nb], accl[mb][nb], 0, 0, 0);
                    accl[mb][nb] = __builtin_amdgcn_mfma_f32_32x32x16_f16(
                        a_lo[mb], bh1[nb], accl[mb][nb], 0, 0, 0);
                }
        }
    }

    // ---- epilogue: C/D layout col=lane&31, row=(reg&3)+8*(reg>>2)+4*q ----
#pragma unroll
    for (int mb = 0; mb < 2; ++mb)
#pragma unroll
        for (int nb = 0; nb < 2; ++nb) {
            const int n = bn + wv * 64 + nb * 32 + m_;
#pragma unroll
            for (int reg = 0; reg < 16; ++reg) {
                const int row = (reg & 3) + 8 * (reg >> 2) + 4 * q;
                const int m = bm + mb * 32 + row;
                C[(size_t)m * D2 + n] = accm[mb][nb][reg] + accl[mb][nb][reg] * (1.0f / 2048.0f);
            }
        }
}

// ---------------------------------------------------------------------------
// Scan: sequential in t, parallel over (b,d2). 8-deep load pipeline:
// ~8 loads in flight per wave -> ~16 KB/CU outstanding.
// ---------------------------------------------------------------------------
__global__ __launch_bounds__(256) void scan_kernel(float* __restrict__ out) {
    const int j = blockIdx.x * 256 + threadIdx.x;
    float* spk = out;
    float* V = out + TT * SS;
    float* I = out + 2 * TT * SS;

    spk[j] = 0.0f;
    V[j] = 0.0f;
    I[j] = 0.0f;

    float syn = 0.0f, mem = 0.0f;

#define STEP(tt, cc)                                     \
    {                                                    \
        const float reset = (mem > 1.0f) ? 1.0f : 0.0f;  \
        syn = ALPHA * syn + (cc);                        \
        mem = (BETA * mem + syn) * (1.0f - reset);       \
        const int idx = (tt) * SS + j;                   \
        spk[idx] = (mem > 1.0f) ? 1.0f : 0.0f;           \
        V[idx] = mem;                                    \
        I[idx] = syn;                                    \
    }

    float c[8];
#pragma unroll
    for (int i = 0; i < 8; ++i) c[i] = I[(1 + i) * SS + j];

    int t = 1;
    for (; t <= 105; t += 8) {
        float nx[8];
#pragma unroll
        for (int i = 0; i < 8; ++i) nx[i] = I[(t + 8 + i) * SS + j];
#pragma unroll
        for (int i = 0; i < 8; ++i) STEP(t + i, c[i]);
#pragma unroll
        for (int i = 0; i < 8; ++i) c[i] = nx[i];
    }
    // t == 113: c holds cur for 113..120
    {
        float nx[7];
#pragma unroll
        for (int i = 0; i < 7; ++i) nx[i] = I[(121 + i) * SS + j];
#pragma unroll
        for (int i = 0; i < 8; ++i) STEP(113 + i, c[i]);
#pragma unroll
        for (int i = 0; i < 7; ++i) STEP(121 + i, nx[i]);
    }
#undef STEP
}

extern "C" void kernel_launch(void* const* d_in, const int* in_sizes, int n_in,
                              void* d_out, int out_size, void* d_ws, size_t ws_size,
                              hipStream_t stream) {
    const float* input = (const float*)d_in[0];   // [128,256,1024]
    const float* weight = (const float*)d_in[1];  // [512,1024]
    float* out = (float*)d_out;

    // f16 hi/lo W planes stashed in spk slices 1..4 (2 MB); gemm reads them
    // from L2, scan overwrites them afterwards.
    _Float16* Whi = (_Float16*)(out + SS);
    _Float16* Wlo = Whi + (size_t)D2 * D1;

    // cur for scan step t at I-region slice t (shift by one slice)
    float* Cdst = out + (size_t)2 * TT * SS + SS;

    convert_w<<<dim3((D2 * D1 / 4) / 256), dim3(256), 0, stream>>>(weight, Whi, Wlo);
    gemm_mfma<<<dim3(MM / BM, D2 / BN), dim3(256), 0, stream>>>(input, Whi, Wlo, Cdst);
    scan_kernel<<<dim3(SS / 256), dim3(256), 0, stream>>>(out);
}